// Round 1
// baseline (440.172 us; speedup 1.0000x reference)
//
#include <hip/hip_runtime.h>
#include <math.h>

// Blocksparse softmax, causal block-tril layout.
// B=8, R=C=64, BS=64, n_blocks = 8 * 2080 = 16640.
// Block (b,r,c), c<=r lives at linear index b*2080 + r*(r+1)/2 + c.
// One workgroup (256 threads) per dense row (b, r, i): row has (r+1)*64
// active columns = (r+1)*16 float4 <= 1024, i.e. <= 4 float4/thread.
// v[4] uses ONLY compile-time indices so it stays in VGPRs (dynamic
// indexing would spill to scratch = global memory traffic).

__global__ __launch_bounds__(256) void bs_softmax_kernel(
    const float* __restrict__ x, float* __restrict__ out) {
    const int bid = blockIdx.x;          // 0 .. 8*64*64-1
    const int i   = bid & 63;            // row within block
    const int r   = 63 - ((bid >> 6) & 63); // block row, big rows dispatched first
    const int b   = bid >> 12;           // batch

    // All addressing fits in int: 16640*4096 = 68,157,440 < 2^31.
    const int base = (b * 2080 + ((r * (r + 1)) >> 1)) * 4096 + i * 64;
    const int nvec = (r + 1) << 4;       // float4 count in this dense row

    const int t = threadIdx.x;

    float4 v[4];
    float m = -INFINITY;

    // Phase 1: load row into registers (compile-time indexed), local max.
    #pragma unroll
    for (int k = 0; k < 4; ++k) {
        const int vi = t + (k << 8);
        if (vi < nvec) {
            const int col = vi << 2;
            const int cb  = col >> 6;        // sparse block along the row
            const int j   = col & 63;        // column inside block
            const float4 val = *(const float4*)(x + base + cb * 4096 + j);
            v[k] = val;
            m = fmaxf(m, fmaxf(fmaxf(val.x, val.y), fmaxf(val.z, val.w)));
        } else {
            v[k] = make_float4(-INFINITY, -INFINITY, -INFINITY, -INFINITY);
        }
    }

    // Wave64 max reduce, then cross-wave via LDS.
    #pragma unroll
    for (int off = 32; off >= 1; off >>= 1)
        m = fmaxf(m, __shfl_xor(m, off, 64));
    __shared__ float sm[4];
    __shared__ float ss[4];
    const int wave = t >> 6;
    if ((t & 63) == 0) sm[wave] = m;
    __syncthreads();
    m = fmaxf(fmaxf(sm[0], sm[1]), fmaxf(sm[2], sm[3]));

    // Phase 2: exp in registers, local sum. Inactive slots are -inf -> 0.
    float s = 0.0f;
    #pragma unroll
    for (int k = 0; k < 4; ++k) {
        float4 val = v[k];
        val.x = __expf(val.x - m);
        val.y = __expf(val.y - m);
        val.z = __expf(val.z - m);
        val.w = __expf(val.w - m);
        v[k] = val;
        s += (val.x + val.y) + (val.z + val.w);
    }
    #pragma unroll
    for (int off = 32; off >= 1; off >>= 1)
        s += __shfl_xor(s, off, 64);
    if ((t & 63) == 0) ss[wave] = s;
    __syncthreads();
    s = (ss[0] + ss[1]) + (ss[2] + ss[3]);
    const float inv = 1.0f / s;

    // Phase 3: scale + store (predicated, compile-time indexed).
    #pragma unroll
    for (int k = 0; k < 4; ++k) {
        const int vi = t + (k << 8);
        if (vi < nvec) {
            const int col = vi << 2;
            const int cb  = col >> 6;
            const int j   = col & 63;
            float4 val = v[k];
            val.x *= inv; val.y *= inv; val.z *= inv; val.w *= inv;
            *(float4*)(out + base + cb * 4096 + j) = val;
        }
    }
}

extern "C" void kernel_launch(void* const* d_in, const int* in_sizes, int n_in,
                              void* d_out, int out_size, void* d_ws, size_t ws_size,
                              hipStream_t stream) {
    const float* x = (const float*)d_in[0];
    float* out = (float*)d_out;
    // 8 batches * 64 block-rows * 64 rows-per-block = 32768 dense rows.
    dim3 grid(8 * 64 * 64);
    dim3 block(256);
    bs_softmax_kernel<<<grid, block, 0, stream>>>(x, out);
}

// Round 2
// 436.434 us; speedup vs baseline: 1.0086x; 1.0086x over previous
//
#include <hip/hip_runtime.h>
#include <math.h>

// Blocksparse softmax, causal block-tril layout.
// B=8, R=C=64, BS=64, n_blocks = 8 * 2080 = 16640.
// Block (b,r,c), c<=r lives at linear index b*2080 + r*(r+1)/2 + c.
//
// WAVE-PER-ROW version: one wave64 owns one dense row (b, r, i).
// Longest row (r=63) has 64 blocks * 64 cols = 4096 floats = 1024 float4
// -> 16 float4 per lane (64 VGPRs of data, compile-time indexed only).
// Reductions are pure __shfl_xor within the wave: NO __syncthreads, NO LDS,
// so no vmcnt(0) barrier drains; 16 loads in flight per wave (vs 4 before).
// 4 independent waves per 256-thread WG; consecutive waves get consecutive
// rows i of the same (b, r) -> equal length, balanced retire.

__global__ __launch_bounds__(256) void bs_softmax_kernel(
    const float* __restrict__ x, float* __restrict__ out) {
    const int w    = (blockIdx.x << 2) + (threadIdx.x >> 6); // dense row id
    const int lane = threadIdx.x & 63;

    const int i = w & 63;                 // row within block
    const int r = 63 - ((w >> 6) & 63);   // block row, big rows dispatched first
    const int b = w >> 12;                // batch

    // All addressing fits in int: 16640*4096 = 68,157,440 < 2^31.
    const int base = (b * 2080 + ((r * (r + 1)) >> 1)) * 4096 + i * 64;
    const int nvec = (r + 1) << 4;        // float4 count in this dense row

    // vi = lane + 64k -> col = 4*vi; cb = (lane>>4) + 4k; j = (4*lane) & 63.
    // Per-k float offset from the lane's k=0 address is exactly k*16384.
    const int j   = (lane << 2) & 63;
    const int cb0 = lane >> 4;
    const float* p0 = x + base + cb0 * 4096 + j;

    float4 v[16];
    float m = -INFINITY;

    // Phase 1: load row into registers (compile-time indexed), local max.
    #pragma unroll
    for (int k = 0; k < 16; ++k) {
        const int vi = lane + (k << 6);
        if (vi < nvec) {
            const float4 val = *(const float4*)(p0 + k * 16384);
            v[k] = val;
            m = fmaxf(m, fmaxf(fmaxf(val.x, val.y), fmaxf(val.z, val.w)));
        } else {
            v[k] = make_float4(-INFINITY, -INFINITY, -INFINITY, -INFINITY);
        }
    }

    // Wave64 max reduce (no LDS, no barrier).
    #pragma unroll
    for (int off = 32; off >= 1; off >>= 1)
        m = fmaxf(m, __shfl_xor(m, off, 64));

    // Phase 2: exp in registers, local sum. Inactive slots are -inf -> 0.
    float s = 0.0f;
    #pragma unroll
    for (int k = 0; k < 16; ++k) {
        float4 val = v[k];
        val.x = __expf(val.x - m);
        val.y = __expf(val.y - m);
        val.z = __expf(val.z - m);
        val.w = __expf(val.w - m);
        v[k] = val;
        s += (val.x + val.y) + (val.z + val.w);
    }
    #pragma unroll
    for (int off = 32; off >= 1; off >>= 1)
        s += __shfl_xor(s, off, 64);
    const float inv = 1.0f / s;

    // Phase 3: scale + store (predicated, compile-time indexed).
    float* q0 = out + base + cb0 * 4096 + j;
    #pragma unroll
    for (int k = 0; k < 16; ++k) {
        const int vi = lane + (k << 6);
        if (vi < nvec) {
            float4 val = v[k];
            val.x *= inv; val.y *= inv; val.z *= inv; val.w *= inv;
            *(float4*)(q0 + k * 16384) = val;
        }
    }
}

extern "C" void kernel_launch(void* const* d_in, const int* in_sizes, int n_in,
                              void* d_out, int out_size, void* d_ws, size_t ws_size,
                              hipStream_t stream) {
    const float* x = (const float*)d_in[0];
    float* out = (float*)d_out;
    // 8 batches * 64 block-rows * 64 rows-per-block = 32768 dense rows,
    // 4 waves (rows) per 256-thread workgroup.
    dim3 grid(8 * 64 * 64 / 4);
    dim3 block(256);
    bs_softmax_kernel<<<grid, block, 0, stream>>>(x, out);
}

// Round 3
// 435.791 us; speedup vs baseline: 1.0101x; 1.0015x over previous
//
#include <hip/hip_runtime.h>
#include <math.h>

// Blocksparse softmax, causal block-tril layout.
// B=8, R=C=64, BS=64, n_blocks = 8 * 2080 = 16640.
// Block (b,r,c), c<=r lives at linear index b*2080 + r*(r+1)/2 + c.
//
// ROW-QUAD version: one WG (256 threads, 4 waves) handles 4 consecutive
// dense rows (4*i0 .. 4*i0+3) of block-row (b, r). Wave w covers blocks
// c = w, w+4, w+8, ...  Each wave load is ONE block's 4-row slab:
// lane -> row 4*i0 + (lane>>4), cols (lane&15)*4 .. +3, i.e. 64 lanes
// x 16 B = 1 KB FULLY CONTIGUOUS per wave instruction (vs 4 scattered
// 256 B segments before) -> better HBM row locality.
// Per-row reduce: 16-lane __shfl_xor; cross-wave via tiny LDS (2 barriers).
// k-predicate (c <= r) is wave-uniform -> scalar branch, no divergence.
// v[16] uses ONLY compile-time indices so it stays in VGPRs.

__global__ __launch_bounds__(256) void bs_softmax_kernel(
    const float* __restrict__ x, float* __restrict__ out) {
    const int wg   = blockIdx.x;            // 0 .. 8*64*16-1
    const int i0   = wg & 15;               // row-quad within block-row
    const int r    = 63 - ((wg >> 4) & 63); // block row, big rows first
    const int b    = wg >> 10;              // batch

    const int w    = threadIdx.x >> 6;      // wave 0..3
    const int lane = threadIdx.x & 63;
    const int lr   = lane >> 4;             // local row 0..3
    const int jj   = (lane & 15) << 2;      // col within block row

    // float offset of (block c, row 4*i0+lr, col jj):
    //   (blk0 + c)*4096 + (4*i0+lr)*64 + jj      (all fits in int)
    const int blk0 = b * 2080 + ((r * (r + 1)) >> 1);
    const int off0 = blk0 * 4096 + (((i0 << 2) + lr) << 6) + jj;
    const float* p0 = x + off0;

    // wave w's block count: c = w + 4k <= r
    const int nb = (r >= w) ? (((r - w) >> 2) + 1) : 0;

    float4 v[16];
    float m = -INFINITY;

    // Phase 1: load (1 KB contiguous per wave instruction), local max.
    #pragma unroll
    for (int k = 0; k < 16; ++k) {
        if (k < nb) {                        // wave-uniform predicate
            const float4 val = *(const float4*)(p0 + ((w + (k << 2)) << 12));
            v[k] = val;
            m = fmaxf(m, fmaxf(fmaxf(val.x, val.y), fmaxf(val.z, val.w)));
        } else {
            v[k] = make_float4(-INFINITY, -INFINITY, -INFINITY, -INFINITY);
        }
    }

    // Row-max across the 16-lane group (xor bits 0..3 stay in-group).
    #pragma unroll
    for (int off = 8; off >= 1; off >>= 1)
        m = fmaxf(m, __shfl_xor(m, off, 64));

    // Cross-wave combine via LDS: red[wave][lr].
    __shared__ float redm[4][4];
    __shared__ float reds[4][4];
    if ((lane & 15) == 0) redm[w][lr] = m;
    __syncthreads();
    m = fmaxf(fmaxf(redm[0][lr], redm[1][lr]), fmaxf(redm[2][lr], redm[3][lr]));

    // Phase 2: exp in registers, local sum. Inactive slots are -inf -> 0.
    float s = 0.0f;
    #pragma unroll
    for (int k = 0; k < 16; ++k) {
        float4 val = v[k];
        val.x = __expf(val.x - m);
        val.y = __expf(val.y - m);
        val.z = __expf(val.z - m);
        val.w = __expf(val.w - m);
        v[k] = val;
        s += (val.x + val.y) + (val.z + val.w);
    }
    #pragma unroll
    for (int off = 8; off >= 1; off >>= 1)
        s += __shfl_xor(s, off, 64);
    if ((lane & 15) == 0) reds[w][lr] = s;
    __syncthreads();
    s = (reds[0][lr] + reds[1][lr]) + (reds[2][lr] + reds[3][lr]);
    const float inv = 1.0f / s;

    // Phase 3: scale + store (1 KB contiguous per wave instruction).
    float* q0 = out + off0;
    #pragma unroll
    for (int k = 0; k < 16; ++k) {
        if (k < nb) {
            float4 val = v[k];
            val.x *= inv; val.y *= inv; val.z *= inv; val.w *= inv;
            *(float4*)(q0 + ((w + (k << 2)) << 12)) = val;
        }
    }
}

extern "C" void kernel_launch(void* const* d_in, const int* in_sizes, int n_in,
                              void* d_out, int out_size, void* d_ws, size_t ws_size,
                              hipStream_t stream) {
    const float* x = (const float*)d_in[0];
    float* out = (float*)d_out;
    // 8 batches * 64 block-rows * 16 row-quads = 8192 WGs, 256 threads each.
    dim3 grid(8 * 64 * 16);
    dim3 block(256);
    bs_softmax_kernel<<<grid, block, 0, stream>>>(x, out);
}